// Round 3
// baseline (338.750 us; speedup 1.0000x reference)
//
#include <hip/hip_runtime.h>

// TTLinearR: y = x @ W^T + b, W (4096x4096) = TT ranks [1,64,64,64,64,64,1].
// W = Amat(4096,64) @ Bmat(64,4096) (rank-64 middle factorization):
//   Amat = ((c0r(16,64)@c1r(64,1024)).reshape(256,64)@c2r(64,1024)).reshape(4096,64)
//   S3(1024,16) = c4r(1024,64)@c5r(64,16); Bmat(1024,256) = c3r(1024,64)@S3view(64,256)
// y = (x @ Bmat^T) @ Amat^T + b.  ~8.6 GFLOP; traffic floor ~260 MB (~42 us).
//
// R3 structure: barrier-free fragment-direct MFMA GEMMs.
//  - gemm1: waves load x straight into A-frag layout (fp32->bf16 in reg),
//    Bmat (bf16, 0.5 MB, L2-resident) straight into B-frags. No LDS, no
//    __syncthreads, no atomics -> compiler software-pipelines vmcnt.
//    Split-K=4 into private partial slices.
//  - reduce_t: sum 4 partials -> bf16 t (1 MB).
//  - gemm2: frag-direct from t/Amat (both L2), per-wave LDS transpose so
//    the 128 MB output goes out as global_store_dwordx4.

#define TOK 8192
#define DIN 4096
#define DOUT 4096
#define RNK 64
#define KSPLIT 4

typedef __bf16 bf16x8 __attribute__((ext_vector_type(8)));
typedef float f32x4 __attribute__((ext_vector_type(4)));

__device__ __forceinline__ unsigned short f2bf(float f) {
  unsigned int u = __float_as_uint(f);
  u += 0x7FFFu + ((u >> 16) & 1u);  // RNE
  return (unsigned short)(u >> 16);
}

__device__ __forceinline__ bf16x8 cvt8(float4 a, float4 b) {
  union { unsigned short u[8]; bf16x8 v; } U;
  U.u[0] = f2bf(a.x); U.u[1] = f2bf(a.y); U.u[2] = f2bf(a.z); U.u[3] = f2bf(a.w);
  U.u[4] = f2bf(b.x); U.u[5] = f2bf(b.y); U.u[6] = f2bf(b.z); U.u[7] = f2bf(b.w);
  return U.v;
}

// ---------------- chain: C[M][N] = A[M][64] @ B[64][N], tiny ----------------
__global__ void mm64_kernel(const float* __restrict__ A, const float* __restrict__ B,
                            float* __restrict__ C, int N) {
  int idx = blockIdx.x * 256 + threadIdx.x;
  int m = idx / N;
  int n = idx - m * N;
  const float* a = A + m * 64;
  float acc = 0.f;
#pragma unroll
  for (int k = 0; k < 64; ++k) acc += a[k] * B[k * N + n];
  C[idx] = acc;
}

__global__ void mm64_bf16_kernel(const float* __restrict__ A, const float* __restrict__ B,
                                 unsigned short* __restrict__ C, int N) {
  int idx = blockIdx.x * 256 + threadIdx.x;
  int m = idx / N;
  int n = idx - m * N;
  const float* a = A + m * 64;
  float acc = 0.f;
#pragma unroll
  for (int k = 0; k < 64; ++k) acc += a[k] * B[k * N + n];
  C[idx] = f2bf(acc);
}

// ---- GEMM1: t_part[z](8192,64) = x(:,zK:..) @ Bmat(:,zK:..)^T, no LDS -----
// grid (KSPLIT, TOK/64), 256 thr = 4 waves; wave handles 16 tokens x 64 ranks.
__global__ __launch_bounds__(256)
void gemm1_mfma(const float* __restrict__ x, const unsigned short* __restrict__ Bbf,
                float* __restrict__ t_part) {
  const int tid = threadIdx.x;
  const int w = tid >> 6, lane = tid & 63;
  const int r = lane & 15, q = lane >> 4;
  const int z = blockIdx.x;
  const int m0 = blockIdx.y * 64 + w * 16;
  const int kbase = z * (DIN / KSPLIT);

  f32x4 acc[4];
#pragma unroll
  for (int j = 0; j < 4; ++j) acc[j] = (f32x4){0.f, 0.f, 0.f, 0.f};

  // A-frag: A[m = lane&15][k = q*8 + jj] ; B-frag: B[n = lane&15][k = q*8 + jj]
  const float* xrow = x + (size_t)(m0 + r) * DIN + kbase + q * 8;
  const unsigned short* brow = Bbf + (size_t)r * DIN + kbase + q * 8;

#pragma unroll 4
  for (int s = 0; s < (DIN / KSPLIT) / 32; ++s) {  // 32 k-steps of 32
    float4 xa = *(const float4*)(xrow + s * 32);
    float4 xb = *(const float4*)(xrow + s * 32 + 4);
    bf16x8 a = cvt8(xa, xb);
#pragma unroll
    for (int j = 0; j < 4; ++j) {
      bf16x8 b = *(const bf16x8*)(brow + (size_t)j * 16 * DIN + s * 32);
      acc[j] = __builtin_amdgcn_mfma_f32_16x16x32_bf16(a, b, acc[j], 0, 0, 0);
    }
  }
  // C/D: col = lane&15 (rank), row = q*4 + i (token). Exclusive writes.
  float* tp = t_part + ((size_t)z * TOK + m0 + q * 4) * RNK + r;
#pragma unroll
  for (int j = 0; j < 4; ++j)
#pragma unroll
    for (int i = 0; i < 4; ++i)
      tp[(size_t)i * RNK + j * 16] = acc[j][i];
}

// ---------------- reduce: t_bf16 = bf16( sum_z t_part[z] ) ------------------
__global__ void reduce_t(const float* __restrict__ t_part, unsigned short* __restrict__ tbf) {
  int i4 = (blockIdx.x * 256 + threadIdx.x) * 4;
  float4 s = *(const float4*)&t_part[i4];
#pragma unroll
  for (int z = 1; z < KSPLIT; ++z) {
    float4 p = *(const float4*)&t_part[(size_t)z * TOK * RNK + i4];
    s.x += p.x; s.y += p.y; s.z += p.z; s.w += p.w;
  }
  ushort4 h = {f2bf(s.x), f2bf(s.y), f2bf(s.z), f2bf(s.w)};
  *(ushort4*)&tbf[i4] = h;
}

// ---- GEMM2: y(8192,4096) = t(8192,64) @ Amat(4096,64)^T + b, frag-direct ---
// grid (DOUT/64, TOK/64), 4 waves; wave = 16 tokens x 64 cols. LDS only for
// the output transpose so stores are dwordx4.
#define LSTR 68  // dword stride: 16B-aligned rows, banks shift 4/row
__global__ __launch_bounds__(256)
void gemm2_mfma(const unsigned short* __restrict__ tbf, const unsigned short* __restrict__ Abf,
                const float* __restrict__ bias, float* __restrict__ out) {
  __shared__ float lds[4 * 16 * LSTR];
  const int tid = threadIdx.x;
  const int w = tid >> 6, lane = tid & 63;
  const int r = lane & 15, q = lane >> 4;
  const int n0 = blockIdx.x * 64;
  const int m0 = blockIdx.y * 64 + w * 16;

  f32x4 acc[4];
#pragma unroll
  for (int j = 0; j < 4; ++j) acc[j] = (f32x4){0.f, 0.f, 0.f, 0.f};

#pragma unroll
  for (int s32 = 0; s32 < 2; ++s32) {
    bf16x8 a = *(const bf16x8*)&tbf[(size_t)(m0 + r) * RNK + s32 * 32 + q * 8];
#pragma unroll
    for (int j = 0; j < 4; ++j) {
      bf16x8 b = *(const bf16x8*)&Abf[(size_t)(n0 + j * 16 + r) * RNK + s32 * 32 + q * 8];
      acc[j] = __builtin_amdgcn_mfma_f32_16x16x32_bf16(a, b, acc[j], 0, 0, 0);
    }
  }

  // bias + scatter to LDS in output layout (row = token, col contiguous)
  float* L = lds + w * 16 * LSTR;
#pragma unroll
  for (int j = 0; j < 4; ++j) {
    float bb = bias[n0 + j * 16 + r];
#pragma unroll
    for (int i = 0; i < 4; ++i)
      L[(q * 4 + i) * LSTR + j * 16 + r] = acc[j][i] + bb;
  }
  __syncthreads();
  // lane -> (row = lane&15, 16-col chunk = lane>>4); 4x dwordx4 out
  const float* Lr = lds + w * 16 * LSTR + r * LSTR + q * 16;
  float* og = out + (size_t)(m0 + r) * DOUT + n0 + q * 16;
#pragma unroll
  for (int c = 0; c < 4; ++c)
    *(float4*)(og + c * 4) = *(const float4*)(Lr + c * 4);
}

extern "C" void kernel_launch(void* const* d_in, const int* in_sizes, int n_in,
                              void* d_out, int out_size, void* d_ws, size_t ws_size,
                              hipStream_t stream) {
  const float* c0 = (const float*)d_in[0];
  const float* c1 = (const float*)d_in[1];
  const float* c2 = (const float*)d_in[2];
  const float* c3 = (const float*)d_in[3];
  const float* c4 = (const float*)d_in[4];
  const float* c5 = (const float*)d_in[5];
  const float* x  = (const float*)d_in[6];
  const float* bias = (const float*)d_in[7];
  float* out = (float*)d_out;

  char* ws = (char*)d_ws;
  float*          t_part = (float*)(ws);                        // 4*8192*64*4 = 8 MB
  unsigned short* tbf    = (unsigned short*)(ws + (8u << 20));  // 1 MB
  unsigned short* Abf    = (unsigned short*)(ws + (9u << 20));  // 0.5 MB
  unsigned short* Bbf    = (unsigned short*)(ws + (9u << 20) + (1u << 19));  // 0.5 MB
  float*          S1     = (float*)(ws + (10u << 20));          // 64 KB
  float*          S3     = (float*)(ws + (10u << 20) + (1u << 16));  // 64 KB

  // rank-64 factorization chain (tiny); final factors emitted in bf16
  mm64_kernel<<<(16 * 1024) / 256, 256, 0, stream>>>(c0, c1, S1, 1024);
  mm64_bf16_kernel<<<(256 * 1024) / 256, 256, 0, stream>>>(S1, c2, Abf, 1024);
  mm64_kernel<<<(1024 * 16) / 256, 256, 0, stream>>>(c4, c5, S3, 16);
  mm64_bf16_kernel<<<(1024 * 256) / 256, 256, 0, stream>>>(c3, S3, Bbf, 256);

  // t_part = x @ Bmat^T (read-bound: 128 MB of x), barrier-free split-K
  gemm1_mfma<<<dim3(KSPLIT, TOK / 64), 256, 0, stream>>>(x, Bbf, t_part);

  // t = sum of partials, in bf16
  reduce_t<<<(TOK * RNK / 4) / 256, 256, 0, stream>>>(t_part, tbf);

  // y = t @ Amat^T + b (write-bound: 128 MB), vectorized stores
  gemm2_mfma<<<dim3(DOUT / 64, TOK / 64), 256, 0, stream>>>(tbf, Abf, bias, out);
}

// Round 4
// 281.562 us; speedup vs baseline: 1.2031x; 1.2031x over previous
//
#include <hip/hip_runtime.h>

// TTLinearR: y = x @ W^T + b, W (4096x4096) = TT ranks [1,64,64,64,64,64,1].
// W = Amat(4096,64) @ Bmat(64,4096) (rank-64 middle factorization):
//   Amat = ((c0r(16,64)@c1r(64,1024)).reshape(256,64)@c2r(64,1024)).reshape(4096,64)
//   S3(1024,16) = c4r(1024,64)@c5r(64,16); Bmat(1024,256) = c3r(1024,64)@S3view(64,256)
// y = (x @ Bmat^T) @ Amat^T + b.  ~8.6 GFLOP; traffic floor ~260 MB (~42 us).
//
// R4 = R2 structure (LDS-staged MFMA GEMMs — measured best) minus its known
// costs: split-K partials instead of 8-way-contended atomics (+ no memset),
// factors pre-converted to bf16 (half the staging bytes), gemm2 reads bf16 t.

#define TOK 8192
#define DIN 4096
#define DOUT 4096
#define RNK 64
#define KSPLIT 8

typedef __bf16 bf16x8 __attribute__((ext_vector_type(8)));
typedef float f32x4 __attribute__((ext_vector_type(4)));

__device__ __forceinline__ unsigned short f2bf(float f) {
  unsigned int u = __float_as_uint(f);
  u += 0x7FFFu + ((u >> 16) & 1u);  // RNE
  return (unsigned short)(u >> 16);
}

// ---------------- chain: C[M][N] = A[M][64] @ B[64][N], tiny ----------------
__global__ void mm64_kernel(const float* __restrict__ A, const float* __restrict__ B,
                            float* __restrict__ C, int N) {
  int idx = blockIdx.x * 256 + threadIdx.x;
  int m = idx / N;
  int n = idx - m * N;
  const float* a = A + m * 64;
  float acc = 0.f;
#pragma unroll
  for (int k = 0; k < 64; ++k) acc += a[k] * B[k * N + n];
  C[idx] = acc;
}

__global__ void mm64_bf16_kernel(const float* __restrict__ A, const float* __restrict__ B,
                                 unsigned short* __restrict__ C, int N) {
  int idx = blockIdx.x * 256 + threadIdx.x;
  int m = idx / N;
  int n = idx - m * N;
  const float* a = A + m * 64;
  float acc = 0.f;
#pragma unroll
  for (int k = 0; k < 64; ++k) acc += a[k] * B[k * N + n];
  C[idx] = f2bf(acc);
}

// ---- GEMM1: t_part[z](8192,64) = x(:, z*512..) @ Bmat(:, z*512..)^T --------
// grid (1, 128, 8): by = 64-token tile, bz = K-split. Exclusive partial writes.
#define G1_SX 136  // 128 + 8 bf16 pad (row stride 272 B = 17 bank-quads: frag reads spread)
__global__ __launch_bounds__(256)
void gemm1_mfma(const float* __restrict__ x, const unsigned short* __restrict__ Bbf,
                float* __restrict__ t_part) {
  __shared__ unsigned short xs[64 * G1_SX];
  __shared__ unsigned short bs[64 * G1_SX];
  const int tid = threadIdx.x;
  const int m0 = blockIdx.y * 64;
  const int lane = tid & 63, wv = tid >> 6;
  const int r = lane & 15, q = lane >> 4;
  const int z = blockIdx.z;

  f32x4 acc[4];
#pragma unroll
  for (int j = 0; j < 4; ++j) acc[j] = (f32x4){0.f, 0.f, 0.f, 0.f};

  for (int s = 0; s < 4; ++s) {
    const int kbase = z * (DIN / KSPLIT) + s * 128;
    // x tile 64x128: fp32 -> bf16 (coalesced float4 reads)
#pragma unroll
    for (int j = 0; j < 8; ++j) {
      int f = j * 256 + tid;          // 0..2047
      int row = f >> 5, c4 = f & 31;  // 64 rows x 32 float4-chunks
      float4 vx = *(const float4*)&x[(size_t)(m0 + row) * DIN + kbase + c4 * 4];
      ushort4 hx = {f2bf(vx.x), f2bf(vx.y), f2bf(vx.z), f2bf(vx.w)};
      *(ushort4*)&xs[row * G1_SX + c4 * 4] = hx;
    }
    // B tile 64x128 bf16 (L2-resident, uint4 = 8 shorts)
#pragma unroll
    for (int j = 0; j < 4; ++j) {
      int f = j * 256 + tid;          // 0..1023
      int row = f >> 4, c = f & 15;   // 64 rows x 16 uint4-chunks
      *(uint4*)&bs[row * G1_SX + c * 8] =
          *(const uint4*)&Bbf[(size_t)row * DIN + kbase + c * 8];
    }
    __syncthreads();
#pragma unroll
    for (int s32 = 0; s32 < 4; ++s32) {
      bf16x8 a = *(const bf16x8*)&xs[(wv * 16 + r) * G1_SX + s32 * 32 + q * 8];
#pragma unroll
      for (int j = 0; j < 4; ++j) {
        bf16x8 b = *(const bf16x8*)&bs[(j * 16 + r) * G1_SX + s32 * 32 + q * 8];
        acc[j] = __builtin_amdgcn_mfma_f32_16x16x32_bf16(a, b, acc[j], 0, 0, 0);
      }
    }
    __syncthreads();
  }
  // C/D: col = lane&15 (rank), row = q*4 + i (token). Exclusive slice writes.
  float* tp = t_part + ((size_t)z * TOK + m0 + wv * 16 + q * 4) * RNK + r;
#pragma unroll
  for (int j = 0; j < 4; ++j)
#pragma unroll
    for (int i = 0; i < 4; ++i)
      tp[(size_t)i * RNK + j * 16] = acc[j][i];
}

// ---------------- reduce: t_bf16 = bf16( sum_z t_part[z] ) ------------------
__global__ void reduce_t(const float* __restrict__ t_part, unsigned short* __restrict__ tbf) {
  int i4 = (blockIdx.x * 256 + threadIdx.x) * 4;
  float4 s = *(const float4*)&t_part[i4];
#pragma unroll
  for (int z = 1; z < KSPLIT; ++z) {
    float4 p = *(const float4*)&t_part[(size_t)z * TOK * RNK + i4];
    s.x += p.x; s.y += p.y; s.z += p.z; s.w += p.w;
  }
  ushort4 h = {f2bf(s.x), f2bf(s.y), f2bf(s.z), f2bf(s.w)};
  *(ushort4*)&tbf[i4] = h;
}

// ---- GEMM2: y(8192,4096) = t(8192,64) @ Amat(4096,64)^T + b ---------------
// grid (32, 64): bx = 128-col tile, by = 128-token tile. K=64 staged once.
#define G2_S 72  // 64 + 8 bf16 pad (row stride 144 B = 9 bank-quads: frag reads spread)
__global__ __launch_bounds__(256)
void gemm2_mfma(const unsigned short* __restrict__ tbf, const unsigned short* __restrict__ Abf,
                const float* __restrict__ bias, float* __restrict__ out) {
  __shared__ unsigned short ts[128 * G2_S];
  __shared__ unsigned short as_[128 * G2_S];
  const int tid = threadIdx.x;
  const int m0 = blockIdx.y * 128, n0 = blockIdx.x * 128;
  const int lane = tid & 63, wv = tid >> 6;
  const int r = lane & 15, q = lane >> 4;

  // stage t-tile (128x64) and Amat-tile (128x64), both bf16 already
#pragma unroll
  for (int j = 0; j < 4; ++j) {
    int f = j * 256 + tid;         // 0..1023
    int row = f >> 3, c = f & 7;   // 128 rows x 8 uint4-chunks
    *(uint4*)&ts[row * G2_S + c * 8] =
        *(const uint4*)&tbf[(size_t)(m0 + row) * RNK + c * 8];
    *(uint4*)&as_[row * G2_S + c * 8] =
        *(const uint4*)&Abf[(size_t)(n0 + row) * RNK + c * 8];
  }
  __syncthreads();

  const int mw = (wv >> 1) * 64, nw = (wv & 1) * 64;
  f32x4 acc[4][4];
#pragma unroll
  for (int i = 0; i < 4; ++i)
#pragma unroll
    for (int j = 0; j < 4; ++j) acc[i][j] = (f32x4){0.f, 0.f, 0.f, 0.f};

#pragma unroll
  for (int s32 = 0; s32 < 2; ++s32) {
    bf16x8 a[4], b[4];
#pragma unroll
    for (int i = 0; i < 4; ++i)
      a[i] = *(const bf16x8*)&ts[(mw + i * 16 + r) * G2_S + s32 * 32 + q * 8];
#pragma unroll
    for (int j = 0; j < 4; ++j)
      b[j] = *(const bf16x8*)&as_[(nw + j * 16 + r) * G2_S + s32 * 32 + q * 8];
#pragma unroll
    for (int i = 0; i < 4; ++i)
#pragma unroll
      for (int j = 0; j < 4; ++j)
        acc[i][j] = __builtin_amdgcn_mfma_f32_16x16x32_bf16(a[i], b[j], acc[i][j], 0, 0, 0);
  }

  float bb[4];
#pragma unroll
  for (int j = 0; j < 4; ++j) bb[j] = bias[n0 + nw + j * 16 + r];

#pragma unroll
  for (int i = 0; i < 4; ++i)
#pragma unroll
    for (int reg = 0; reg < 4; ++reg) {
      size_t rowg = (size_t)(m0 + mw + i * 16 + q * 4 + reg) * DOUT;
#pragma unroll
      for (int j = 0; j < 4; ++j)
        out[rowg + n0 + nw + j * 16 + r] = acc[i][j][reg] + bb[j];
    }
}

extern "C" void kernel_launch(void* const* d_in, const int* in_sizes, int n_in,
                              void* d_out, int out_size, void* d_ws, size_t ws_size,
                              hipStream_t stream) {
  const float* c0 = (const float*)d_in[0];
  const float* c1 = (const float*)d_in[1];
  const float* c2 = (const float*)d_in[2];
  const float* c3 = (const float*)d_in[3];
  const float* c4 = (const float*)d_in[4];
  const float* c5 = (const float*)d_in[5];
  const float* x  = (const float*)d_in[6];
  const float* bias = (const float*)d_in[7];
  float* out = (float*)d_out;

  char* ws = (char*)d_ws;
  float*          t_part = (float*)(ws);                         // 8*8192*64*4 = 16 MB
  unsigned short* tbf    = (unsigned short*)(ws + (16u << 20));  // 1 MB
  unsigned short* Abf    = (unsigned short*)(ws + (17u << 20));  // 0.5 MB
  unsigned short* Bbf    = (unsigned short*)(ws + (17u << 20) + (1u << 19));  // 0.5 MB
  float*          S1     = (float*)(ws + (18u << 20));           // 64 KB
  float*          S3     = (float*)(ws + (18u << 20) + (1u << 16));  // 64 KB

  // rank-64 factorization chain (tiny); final factors emitted in bf16
  mm64_kernel<<<(16 * 1024) / 256, 256, 0, stream>>>(c0, c1, S1, 1024);
  mm64_bf16_kernel<<<(256 * 1024) / 256, 256, 0, stream>>>(S1, c2, Abf, 1024);
  mm64_kernel<<<(1024 * 16) / 256, 256, 0, stream>>>(c4, c5, S3, 16);
  mm64_bf16_kernel<<<(1024 * 256) / 256, 256, 0, stream>>>(c3, S3, Bbf, 256);

  // t_part = x @ Bmat^T per K-slice (read-bound: 128 MB of x), no atomics
  gemm1_mfma<<<dim3(1, TOK / 64, KSPLIT), 256, 0, stream>>>(x, Bbf, t_part);

  // t = sum of partials -> bf16
  reduce_t<<<(TOK * RNK / 4) / 256, 256, 0, stream>>>(t_part, tbf);

  // y = t @ Amat^T + b (write-bound: 128 MB)
  gemm2_mfma<<<dim3(DOUT / 128, TOK / 128), 256, 0, stream>>>(tbf, Abf, bias, out);
}